// Round 1
// baseline (1396.447 us; speedup 1.0000x reference)
//
#include <hip/hip_runtime.h>

#define FEATS 64

// Fused: (optional prev-layer epilogue: relu(v*norm + b_prev)) -> scale by norm -> @W
// One wave per node; lane j computes output feature j. W staged in LDS.
__global__ void proj_kernel(const float* __restrict__ in, const float* __restrict__ norm,
                            const float* __restrict__ W, const float* __restrict__ bias,
                            float* __restrict__ out, int N, int mode) {
    __shared__ float sW[FEATS * FEATS];
    for (int i = threadIdx.x; i < FEATS * FEATS; i += blockDim.x) sW[i] = W[i];
    __syncthreads();

    const int lane = threadIdx.x & 63;
    const int wid  = threadIdx.x >> 6;
    const int wpb  = blockDim.x >> 6;
    const int node = blockIdx.x * wpb + wid;
    if (node >= N) return;

    const float nv = norm[node];
    float v = in[(size_t)node * FEATS + lane];
    if (mode) v = fmaxf(fmaf(v, nv, bias[lane]), 0.0f);  // prev layer: agg*norm + b, relu
    v *= nv;                                             // this layer's pre-scale

    float acc = 0.0f;
#pragma unroll
    for (int k = 0; k < FEATS; ++k) {
        const float xk = __shfl(v, k, 64);
        acc = fmaf(xk, sW[k * FEATS + lane], acc);
    }
    out[(size_t)node * FEATS + lane] = acc;
}

// One wave per edge: lane j moves feature j from src row to dst row (atomic add).
__global__ void agg_kernel(const float* __restrict__ h, const int* __restrict__ src,
                           const int* __restrict__ dst, float* __restrict__ agg, int E) {
    const int lane = threadIdx.x & 63;
    const int edge = (int)(((size_t)blockIdx.x * blockDim.x + threadIdx.x) >> 6);
    if (edge >= E) return;
    const int s = src[edge];
    const int d = dst[edge];
    const float v = h[(size_t)s * FEATS + lane];
    atomicAdd(&agg[(size_t)d * FEATS + lane], v);
}

// Final epilogue (no relu): out = agg*norm + b
__global__ void finish_kernel(const float* __restrict__ agg, const float* __restrict__ norm,
                              const float* __restrict__ bias, float* __restrict__ out, int total) {
    const int idx = blockIdx.x * blockDim.x + threadIdx.x;
    if (idx >= total) return;
    const int node = idx >> 6;
    const int j    = idx & 63;
    out[idx] = fmaf(agg[idx], norm[node], bias[j]);
}

extern "C" void kernel_launch(void* const* d_in, const int* in_sizes, int n_in,
                              void* d_out, int out_size, void* d_ws, size_t ws_size,
                              hipStream_t stream) {
    const float* feat = (const float*)d_in[0];
    const float* norm = (const float*)d_in[1];
    const int*   src  = (const int*)d_in[2];
    const int*   dst  = (const int*)d_in[3];
    const float* W0   = (const float*)d_in[4];
    const float* b0   = (const float*)d_in[5];
    const float* W1   = (const float*)d_in[6];
    const float* b1   = (const float*)d_in[7];
    const float* W2   = (const float*)d_in[8];
    const float* b2   = (const float*)d_in[9];

    float* out = (float*)d_out;
    const int N = in_sizes[0] / FEATS;
    const int E = in_sizes[2];

    float* C = (float*)d_ws;   // aggregation accumulator [N,64]
    float* B = out;            // projection temp [N,64] (d_out reused)

    const dim3 blk(256);
    const int wpb = 256 / 64;
    const int proj_grid = (N + wpb - 1) / wpb;
    const int agg_grid  = (E + wpb - 1) / wpb;
    const int fin_grid  = (N * FEATS + 255) / 256;
    const size_t agg_bytes = (size_t)N * FEATS * sizeof(float);

    // layer 0
    proj_kernel<<<proj_grid, blk, 0, stream>>>(feat, norm, W0, nullptr, B, N, 0);
    hipMemsetAsync(C, 0, agg_bytes, stream);
    agg_kernel<<<agg_grid, blk, 0, stream>>>(B, src, dst, C, E);

    // layer 1 (layer-0 epilogue fused into projection)
    proj_kernel<<<proj_grid, blk, 0, stream>>>(C, norm, W1, b0, B, N, 1);
    hipMemsetAsync(C, 0, agg_bytes, stream);
    agg_kernel<<<agg_grid, blk, 0, stream>>>(B, src, dst, C, E);

    // layer 2
    proj_kernel<<<proj_grid, blk, 0, stream>>>(C, norm, W2, b1, B, N, 1);
    hipMemsetAsync(C, 0, agg_bytes, stream);
    agg_kernel<<<agg_grid, blk, 0, stream>>>(B, src, dst, C, E);

    // final epilogue
    finish_kernel<<<fin_grid, blk, 0, stream>>>(C, norm, b2, out, N * FEATS);
}

// Round 2
// 715.346 us; speedup vs baseline: 1.9521x; 1.9521x over previous
//
#include <hip/hip_runtime.h>

#define FEATS 64

// ---------------- projection: (optional prev epilogue) -> *norm -> @W ----------------
__global__ void proj_kernel(const float* __restrict__ in, const float* __restrict__ norm,
                            const float* __restrict__ W, const float* __restrict__ bias,
                            float* __restrict__ out, int N, int mode) {
    __shared__ float sW[FEATS * FEATS];
    for (int i = threadIdx.x; i < FEATS * FEATS; i += blockDim.x) sW[i] = W[i];
    __syncthreads();

    const int lane = threadIdx.x & 63;
    const int wid  = threadIdx.x >> 6;
    const int wpb  = blockDim.x >> 6;
    const int node = blockIdx.x * wpb + wid;
    if (node >= N) return;

    const float nv = norm[node];
    float v = in[(size_t)node * FEATS + lane];
    if (mode) v = fmaxf(fmaf(v, nv, bias[lane]), 0.0f);  // prev layer: agg*norm + b, relu
    v *= nv;                                             // this layer's pre-scale

    float acc = 0.0f;
#pragma unroll
    for (int k = 0; k < FEATS; ++k) {
        const float xk = __shfl(v, k, 64);
        acc = fmaf(xk, sW[k * FEATS + lane], acc);
    }
    out[(size_t)node * FEATS + lane] = acc;
}

// ---------------- CSR build ----------------
__global__ void hist_kernel(const int* __restrict__ dst, int* __restrict__ deg, int E) {
    int e = blockIdx.x * 256 + threadIdx.x;
    if (e < E) atomicAdd(&deg[dst[e]], 1);
}

// per-block exclusive scan (no base), block totals to bsum
__global__ void scan_block(const int* __restrict__ deg, int* __restrict__ outp,
                           int* __restrict__ bsum, int N) {
    __shared__ int s[256];
    const int tid = threadIdx.x;
    const int i = blockIdx.x * 256 + tid;
    int v = (i < N) ? deg[i] : 0;
    s[tid] = v;
    __syncthreads();
    int x = v;
    for (int off = 1; off < 256; off <<= 1) {
        int y = (tid >= off) ? s[tid - off] : 0;
        __syncthreads();
        x += y;
        s[tid] = x;
        __syncthreads();
    }
    if (i < N) outp[i] = x - v;                 // exclusive within block
    if (tid == 255) bsum[blockIdx.x] = x;       // block total
}

// single-block exclusive scan of block sums (nb <= 512)
__global__ void scan_bsum(int* __restrict__ bsum, int nb) {
    __shared__ int s[512];
    const int tid = threadIdx.x;
    int v = (tid < nb) ? bsum[tid] : 0;
    s[tid] = v;
    __syncthreads();
    int x = v;
    for (int off = 1; off < 512; off <<= 1) {
        int y = (tid >= off) ? s[tid - off] : 0;
        __syncthreads();
        x += y;
        s[tid] = x;
        __syncthreads();
    }
    if (tid < nb) bsum[tid] = x - v;            // exclusive
}

__global__ void add_base(int* __restrict__ rowptr, int* __restrict__ cursor,
                         const int* __restrict__ bsum, int N, int E) {
    const int i = blockIdx.x * 256 + threadIdx.x;
    if (i < N) {
        int r = rowptr[i] + bsum[blockIdx.x];
        rowptr[i] = r;
        cursor[i] = r;
    }
    if (i == 0) rowptr[N] = E;
}

__global__ void scatter_kernel(const int* __restrict__ src, const int* __restrict__ dst,
                               int* __restrict__ cursor, int* __restrict__ csr, int E) {
    int e = blockIdx.x * 256 + threadIdx.x;
    if (e < E) {
        int p = atomicAdd(&cursor[dst[e]], 1);
        csr[p] = src[e];
    }
}

// ---------------- CSR gather-aggregate: one wave per dst node ----------------
// 4 edges per iteration; lane = slot*16 + f4, slot picks edge, f4 picks float4 chunk.
__global__ void agg_csr(const float* __restrict__ h, const int* __restrict__ rowptr,
                        const int* __restrict__ csr, float* __restrict__ agg, int N) {
    const int lane = threadIdx.x & 63;
    const int wid  = threadIdx.x >> 6;
    const int node = blockIdx.x * (blockDim.x >> 6) + wid;
    if (node >= N) return;

    const int beg = rowptr[node];
    const int end = rowptr[node + 1];
    const int slot = lane >> 4;     // 0..3
    const int f4   = lane & 15;     // float4 chunk index

    float4 acc = make_float4(0.f, 0.f, 0.f, 0.f);
    int e = beg;
    for (; e + 4 <= end; e += 4) {
        const int s = csr[e + slot];
        const float4 v = *reinterpret_cast<const float4*>(&h[(size_t)s * FEATS + 4 * f4]);
        acc.x += v.x; acc.y += v.y; acc.z += v.z; acc.w += v.w;
    }
    if (e + slot < end) {
        const int s = csr[e + slot];
        const float4 v = *reinterpret_cast<const float4*>(&h[(size_t)s * FEATS + 4 * f4]);
        acc.x += v.x; acc.y += v.y; acc.z += v.z; acc.w += v.w;
    }
    // reduce across the 4 slots (lane bits 4 and 5)
    acc.x += __shfl_xor(acc.x, 16, 64); acc.y += __shfl_xor(acc.y, 16, 64);
    acc.z += __shfl_xor(acc.z, 16, 64); acc.w += __shfl_xor(acc.w, 16, 64);
    acc.x += __shfl_xor(acc.x, 32, 64); acc.y += __shfl_xor(acc.y, 32, 64);
    acc.z += __shfl_xor(acc.z, 32, 64); acc.w += __shfl_xor(acc.w, 32, 64);

    if (lane < 16) {
        *reinterpret_cast<float4*>(&agg[(size_t)node * FEATS + 4 * lane]) = acc;
    }
}

// ---------------- final epilogue ----------------
__global__ void finish_kernel(const float* __restrict__ agg, const float* __restrict__ norm,
                              const float* __restrict__ bias, float* __restrict__ out, int total) {
    const int idx = blockIdx.x * blockDim.x + threadIdx.x;
    if (idx >= total) return;
    const int node = idx >> 6;
    const int j    = idx & 63;
    out[idx] = fmaf(agg[idx], norm[node], bias[j]);
}

extern "C" void kernel_launch(void* const* d_in, const int* in_sizes, int n_in,
                              void* d_out, int out_size, void* d_ws, size_t ws_size,
                              hipStream_t stream) {
    const float* feat = (const float*)d_in[0];
    const float* norm = (const float*)d_in[1];
    const int*   src  = (const int*)d_in[2];
    const int*   dst  = (const int*)d_in[3];
    const float* W0   = (const float*)d_in[4];
    const float* b0   = (const float*)d_in[5];
    const float* W1   = (const float*)d_in[6];
    const float* b1   = (const float*)d_in[7];
    const float* W2   = (const float*)d_in[8];
    const float* b2   = (const float*)d_in[9];

    float* out = (float*)d_out;
    const int N = in_sizes[0] / FEATS;
    const int E = in_sizes[2];

    // workspace layout
    float* C      = (float*)d_ws;               // [N*64] aggregation accumulator
    int*   csr    = (int*)(C + (size_t)N * FEATS);  // [E] sources bucketed by dst
    int*   rowptr = csr + E;                    // [N+1]
    int*   cursor = rowptr + N + 1;             // [N]
    int*   deg    = cursor + N;                 // [N]
    int*   bsum   = deg + N;                    // [512]

    float* B = out;  // projection temp (d_out reused; final write overwrites it)

    const dim3 blk(256);
    const int wpb = 256 / 64;
    const int proj_grid = (N + wpb - 1) / wpb;
    const int agg_grid  = (N + wpb - 1) / wpb;
    const int edge_grid = (E + 255) / 256;
    const int node_grid = (N + 255) / 256;   // 256-elem blocks over nodes
    const int fin_grid  = (N * FEATS + 255) / 256;

    // ---- build CSR once per call ----
    hipMemsetAsync(deg, 0, (size_t)N * sizeof(int), stream);
    hist_kernel<<<edge_grid, blk, 0, stream>>>(dst, deg, E);
    scan_block<<<node_grid, blk, 0, stream>>>(deg, rowptr, bsum, N);
    scan_bsum<<<1, 512, 0, stream>>>(bsum, node_grid);
    add_base<<<node_grid, blk, 0, stream>>>(rowptr, cursor, bsum, N, E);
    scatter_kernel<<<edge_grid, blk, 0, stream>>>(src, dst, cursor, csr, E);

    // ---- layer 0 ----
    proj_kernel<<<proj_grid, blk, 0, stream>>>(feat, norm, W0, nullptr, B, N, 0);
    agg_csr<<<agg_grid, blk, 0, stream>>>(B, rowptr, csr, C, N);

    // ---- layer 1 ----
    proj_kernel<<<proj_grid, blk, 0, stream>>>(C, norm, W1, b0, B, N, 1);
    agg_csr<<<agg_grid, blk, 0, stream>>>(B, rowptr, csr, C, N);

    // ---- layer 2 ----
    proj_kernel<<<proj_grid, blk, 0, stream>>>(C, norm, W2, b1, B, N, 1);
    agg_csr<<<agg_grid, blk, 0, stream>>>(B, rowptr, csr, C, N);

    // ---- final epilogue ----
    finish_kernel<<<fin_grid, blk, 0, stream>>>(C, norm, b2, out, N * FEATS);
}

// Round 4
// 464.821 us; speedup vs baseline: 3.0043x; 1.5390x over previous
//
#include <hip/hip_runtime.h>

#define FEATS 64
#define TILE 16          // dst nodes per bucket (one WAVE per bucket)
#define MAX_NB 6400      // supports N <= 102400 at TILE=16
#define CH 32768         // edges per build chunk

// ---- proj: out[n] = (in[n]*norm[n]) @ W. LDS-staged input tile, W col in regs ----
__global__ __launch_bounds__(256) void proj_kernel(
    const float* __restrict__ in, const float* __restrict__ norm,
    const float* __restrict__ W, float* __restrict__ out, int N) {
    __shared__ float sIn[64 * FEATS];           // 16 KB
    const int lane  = threadIdx.x & 63;
    const int w     = threadIdx.x >> 6;
    const int node0 = blockIdx.x * 64;

    // stage 64 rows pre-scaled by norm (tail rows staged as 0)
    for (int r = (int)(threadIdx.x >> 4); r < 64; r += 16) {
        const int node = node0 + r;
        const int c4 = (threadIdx.x & 15) * 4;
        float4 v = make_float4(0.f, 0.f, 0.f, 0.f);
        if (node < N) {
            v = *reinterpret_cast<const float4*>(&in[(size_t)node * FEATS + c4]);
            const float nv = norm[node];
            v.x *= nv; v.y *= nv; v.z *= nv; v.w *= nv;
        }
        *reinterpret_cast<float4*>(&sIn[r * FEATS + c4]) = v;
    }
    // W column `lane` into registers (64 VGPRs), coalesced across lanes per k
    float wc[FEATS];
#pragma unroll
    for (int k = 0; k < FEATS; ++k) wc[k] = W[k * FEATS + lane];
    __syncthreads();

    // each wave computes 16 nodes; lane = output feature
    for (int nn = 0; nn < 16; ++nn) {
        const int node = node0 + w * 16 + nn;
        if (node >= N) break;
        const float* row = &sIn[(w * 16 + nn) * FEATS];
        float acc = 0.f;
#pragma unroll
        for (int k = 0; k < FEATS; ++k)
            acc = fmaf(row[k], wc[k], acc);     // wave-uniform LDS broadcast reads
        out[(size_t)node * FEATS + lane] = acc;
    }
}

// ---- build pass 1: per-chunk histogram over dst buckets ----
__global__ __launch_bounds__(1024) void hist_pass(
    const int* __restrict__ dst, int* __restrict__ hist, int E, int NB) {
    __shared__ int lh[MAX_NB];
    for (int i = threadIdx.x; i < NB; i += 1024) lh[i] = 0;
    __syncthreads();
    const int k  = blockIdx.x;
    const int e0 = k * CH, e1 = min(E, e0 + CH);
    for (int e = e0 + threadIdx.x; e < e1; e += 1024)
        atomicAdd(&lh[dst[e] >> 4], 1);
    __syncthreads();
    for (int b = threadIdx.x; b < NB; b += 1024)
        hist[(size_t)k * NB + b] = lh[b];
}

// ---- build pass 2: per-bucket exclusive scan across chunks (in place), totals ----
__global__ __launch_bounds__(256) void bucket_scan(
    int* hist, int* __restrict__ btotal, int NB, int NCHUNK) {
    __shared__ int sa[256], sb[256];
    const int b = blockIdx.x, t = threadIdx.x;
    const int v = (t < NCHUNK) ? hist[(size_t)t * NB + b] : 0;
    sa[t] = v;
    __syncthreads();
    int *cur = sa, *nxt = sb;
    for (int off = 1; off < 256; off <<= 1) {
        nxt[t] = cur[t] + ((t >= off) ? cur[t - off] : 0);
        __syncthreads();
        int* tmp = cur; cur = nxt; nxt = tmp;
    }
    if (t < NCHUNK) hist[(size_t)t * NB + b] = cur[t] - v;   // exclusive
    if (t == 255) btotal[b] = cur[255];
}

// ---- build pass 3: single-block chunked exclusive scan of bucket totals ----
__global__ __launch_bounds__(1024) void base_scan(
    const int* __restrict__ btotal, int* __restrict__ bstart, int NB, int E) {
    __shared__ int sa[1024], sb[1024];
    __shared__ int carry;
    const int t = threadIdx.x;
    if (t == 0) carry = 0;
    __syncthreads();
    for (int base = 0; base < NB; base += 1024) {
        const int i = base + t;
        const int v = (i < NB) ? btotal[i] : 0;
        sa[t] = v;
        __syncthreads();
        int *cur = sa, *nxt = sb;
        for (int off = 1; off < 1024; off <<= 1) {
            nxt[t] = cur[t] + ((t >= off) ? cur[t - off] : 0);
            __syncthreads();
            int* tmp = cur; cur = nxt; nxt = tmp;
        }
        const int c = carry;                     // uniform; written behind barriers
        if (i < NB) bstart[i] = c + cur[t] - v;  // exclusive + carry
        __syncthreads();
        if (t == 1023) carry = c + cur[1023];
        __syncthreads();
    }
    if (t == 0) bstart[NB] = E;
}

// ---- build pass 4: scatter packed (dstlow<<26 | src) via per-block LDS cursors ----
__global__ __launch_bounds__(1024) void scatter_pack(
    const int* __restrict__ src, const int* __restrict__ dst,
    const int* __restrict__ prebase, const int* __restrict__ bstart,
    unsigned int* __restrict__ packed, int E, int NB) {
    __shared__ int cur[MAX_NB];
    const int k = blockIdx.x;
    for (int b = threadIdx.x; b < NB; b += 1024)
        cur[b] = bstart[b] + prebase[(size_t)k * NB + b];
    __syncthreads();
    const int e0 = k * CH, e1 = min(E, e0 + CH);
    for (int e = e0 + threadIdx.x; e < e1; e += 1024) {
        const int d = dst[e];
        const int p = atomicAdd(&cur[d >> 4], 1);
        packed[p] = ((unsigned)(d & 15) << 26) | (unsigned)src[e];
    }
}

// ---- aggregate: ONE WAVE per 16-node bucket, private LDS stripe, no atomics ----
__global__ __launch_bounds__(256) void agg_tile(
    const unsigned int* __restrict__ packed, const int* __restrict__ bstart,
    const float* __restrict__ h, const float* __restrict__ norm,
    const float* __restrict__ bias, float* __restrict__ out, int N, int NB, int relu) {
    __shared__ float acc[4][TILE * FEATS];      // 4 waves x 4 KB, disjoint
    const int lane = threadIdx.x & 63;
    const int w    = threadIdx.x >> 6;
    const int b    = blockIdx.x * 4 + w;        // this wave's bucket
    float* A = acc[w];
#pragma unroll
    for (int i = 0; i < TILE; ++i) A[i * FEATS + lane] = 0.f;
    if (b >= NB) return;

    const int beg = bstart[b], end = bstart[b + 1];
    const float bi = bias[lane];

    int e = beg;
    for (; e + 2 <= end; e += 2) {              // 2-deep pipeline: both loads issue first
        const unsigned v0 = packed[e], v1 = packed[e + 1];
        const float x0 = h[(size_t)(v0 & 0x3FFFFFFu) * FEATS + lane];
        const float x1 = h[(size_t)(v1 & 0x3FFFFFFu) * FEATS + lane];
        A[(v0 >> 26) * FEATS + lane] += x0;     // addresses distinct across lanes
        A[(v1 >> 26) * FEATS + lane] += x1;
    }
    if (e < end) {
        const unsigned v = packed[e];
        A[(v >> 26) * FEATS + lane] += h[(size_t)(v & 0x3FFFFFFu) * FEATS + lane];
    }

    // epilogue: out = act(acc*norm + bias), wave-private, no barrier needed
    const int node0 = b * TILE;
#pragma unroll
    for (int i = 0; i < TILE; ++i) {
        const int node = node0 + i;
        if (node >= N) break;
        float o = fmaf(A[i * FEATS + lane], norm[node], bi);
        if (relu) o = fmaxf(o, 0.f);
        out[(size_t)node * FEATS + lane] = o;
    }
}

extern "C" void kernel_launch(void* const* d_in, const int* in_sizes, int n_in,
                              void* d_out, int out_size, void* d_ws, size_t ws_size,
                              hipStream_t stream) {
    const float* feat = (const float*)d_in[0];
    const float* norm = (const float*)d_in[1];
    const int*   src  = (const int*)d_in[2];
    const int*   dst  = (const int*)d_in[3];
    const float* W0   = (const float*)d_in[4];
    const float* b0   = (const float*)d_in[5];
    const float* W1   = (const float*)d_in[6];
    const float* b1   = (const float*)d_in[7];
    const float* W2   = (const float*)d_in[8];
    const float* b2   = (const float*)d_in[9];

    float* out = (float*)d_out;
    const int N = in_sizes[0] / FEATS;
    const int E = in_sizes[2];
    const int NB = (N + TILE - 1) / TILE;          // 6250
    const int NCHUNK = (E + CH - 1) / CH;          // 49

    // workspace layout (~33.3 MB)
    float*    C      = (float*)d_ws;                       // [N*64]
    unsigned* packed = (unsigned*)(C + (size_t)N * FEATS); // [E]
    int*      hist   = (int*)(packed + E);                 // [NCHUNK*NB]
    int*      btotal = hist + (size_t)NCHUNK * NB;         // [NB]
    int*      bstart = btotal + NB;                        // [NB+1]

    // ---- build bucketed edge list (once, reused by 3 layers) ----
    hist_pass<<<NCHUNK, 1024, 0, stream>>>(dst, hist, E, NB);
    bucket_scan<<<NB, 256, 0, stream>>>(hist, btotal, NB, NCHUNK);
    base_scan<<<1, 1024, 0, stream>>>(btotal, bstart, NB, E);
    scatter_pack<<<NCHUNK, 1024, 0, stream>>>(src, dst, hist, bstart, packed, E, NB);

    const int pgrid = (N + 63) / 64;               // 1563
    const int agrid = (NB + 3) / 4;                // 1563

    // layer 0: proj feat -> C ; agg C -> out (relu, b0)
    proj_kernel<<<pgrid, 256, 0, stream>>>(feat, norm, W0, C, N);
    agg_tile<<<agrid, 256, 0, stream>>>(packed, bstart, C, norm, b0, out, N, NB, 1);

    // layer 1: proj out -> C ; agg C -> out (relu, b1)
    proj_kernel<<<pgrid, 256, 0, stream>>>(out, norm, W1, C, N);
    agg_tile<<<agrid, 256, 0, stream>>>(packed, bstart, C, norm, b1, out, N, NB, 1);

    // layer 2: proj out -> C ; agg C -> out (no relu, b2)
    proj_kernel<<<pgrid, 256, 0, stream>>>(out, norm, W2, C, N);
    agg_tile<<<agrid, 256, 0, stream>>>(packed, bstart, C, norm, b2, out, N, NB, 0);
}

// Round 5
// 355.572 us; speedup vs baseline: 3.9273x; 1.3072x over previous
//
#include <hip/hip_runtime.h>

#define FEATS 64
#define TILE 16          // dst nodes per bucket (one WAVE per bucket)
#define MAX_NB 6400      // supports N <= 102400 at TILE=16
#define CH 32768         // edges per build chunk
#define DEPTH 8          // gather pipeline depth

// ---- scale: hs = feat * norm (float4-vectorized) ----
__global__ __launch_bounds__(256) void scale_kernel(
    const float* __restrict__ feat, const float* __restrict__ norm,
    float* __restrict__ out, int n16) {
    const int i = blockIdx.x * 256 + threadIdx.x;
    if (i >= n16) return;
    float4 v = reinterpret_cast<const float4*>(feat)[i];
    const float nv = norm[i >> 4];
    v.x *= nv; v.y *= nv; v.z *= nv; v.w *= nv;
    reinterpret_cast<float4*>(out)[i] = v;
}

// ---- build pass 1: per-chunk histogram over dst buckets ----
__global__ __launch_bounds__(1024) void hist_pass(
    const int* __restrict__ dst, int* __restrict__ hist, int E, int NB) {
    __shared__ int lh[MAX_NB];
    for (int i = threadIdx.x; i < NB; i += 1024) lh[i] = 0;
    __syncthreads();
    const int k  = blockIdx.x;
    const int e0 = k * CH, e1 = min(E, e0 + CH);
    for (int e = e0 + threadIdx.x; e < e1; e += 1024)
        atomicAdd(&lh[dst[e] >> 4], 1);
    __syncthreads();
    for (int b = threadIdx.x; b < NB; b += 1024)
        hist[(size_t)k * NB + b] = lh[b];
}

// ---- build pass 2: per-bucket exclusive scan across chunks (in place), totals ----
__global__ __launch_bounds__(256) void bucket_scan(
    int* hist, int* __restrict__ btotal, int NB, int NCHUNK) {
    __shared__ int sa[256], sb[256];
    const int b = blockIdx.x, t = threadIdx.x;
    const int v = (t < NCHUNK) ? hist[(size_t)t * NB + b] : 0;
    sa[t] = v;
    __syncthreads();
    int *cur = sa, *nxt = sb;
    for (int off = 1; off < 256; off <<= 1) {
        nxt[t] = cur[t] + ((t >= off) ? cur[t - off] : 0);
        __syncthreads();
        int* tmp = cur; cur = nxt; nxt = tmp;
    }
    if (t < NCHUNK) hist[(size_t)t * NB + b] = cur[t] - v;   // exclusive
    if (t == 255) btotal[b] = cur[255];
}

// ---- build pass 3: single-block chunked exclusive scan of bucket totals ----
__global__ __launch_bounds__(1024) void base_scan(
    const int* __restrict__ btotal, int* __restrict__ bstart, int NB, int E) {
    __shared__ int sa[1024], sb[1024];
    __shared__ int carry;
    const int t = threadIdx.x;
    if (t == 0) carry = 0;
    __syncthreads();
    for (int base = 0; base < NB; base += 1024) {
        const int i = base + t;
        const int v = (i < NB) ? btotal[i] : 0;
        sa[t] = v;
        __syncthreads();
        int *cur = sa, *nxt = sb;
        for (int off = 1; off < 1024; off <<= 1) {
            nxt[t] = cur[t] + ((t >= off) ? cur[t - off] : 0);
            __syncthreads();
            int* tmp = cur; cur = nxt; nxt = tmp;
        }
        const int c = carry;                     // uniform; written behind barriers
        if (i < NB) bstart[i] = c + cur[t] - v;  // exclusive + carry
        __syncthreads();
        if (t == 1023) carry = c + cur[1023];
        __syncthreads();
    }
    if (t == 0) bstart[NB] = E;
}

// ---- build pass 4: scatter packed (dstlow<<26 | src) via per-block LDS cursors ----
__global__ __launch_bounds__(1024) void scatter_pack(
    const int* __restrict__ src, const int* __restrict__ dst,
    const int* __restrict__ prebase, const int* __restrict__ bstart,
    unsigned int* __restrict__ packed, int E, int NB) {
    __shared__ int cur[MAX_NB];
    const int k = blockIdx.x;
    for (int b = threadIdx.x; b < NB; b += 1024)
        cur[b] = bstart[b] + prebase[(size_t)k * NB + b];
    __syncthreads();
    const int e0 = k * CH, e1 = min(E, e0 + CH);
    for (int e = e0 + threadIdx.x; e < e1; e += 1024) {
        const int d = dst[e];
        const int p = atomicAdd(&cur[d >> 4], 1);
        packed[p] = ((unsigned)(d & 15) << 26) | (unsigned)src[e];
    }
}

// ---- fused aggregate + project: one WAVE per 16-node bucket ----
// A[i][:] = sum of scaled src rows for dst node i (LDS, wave-private, lane-column-private)
// epilogue: o = (A[i] @ W)·norm[i] + b ; mode=1: o = relu(o)·norm[i] (next-layer prescale)
__global__ __launch_bounds__(256) void agg_proj(
    const unsigned int* __restrict__ packed, const int* __restrict__ bstart,
    const float* __restrict__ hs, const float* __restrict__ norm,
    const float* __restrict__ W, const float* __restrict__ bias,
    float* __restrict__ out, int N, int NB, int mode) {
    __shared__ float acc[4][TILE * FEATS];      // 4 waves x 4 KB, disjoint stripes
    const int lane = threadIdx.x & 63;
    const int w    = threadIdx.x >> 6;
    const int b    = blockIdx.x * 4 + w;        // this wave's bucket
    float* A = acc[w];
#pragma unroll
    for (int i = 0; i < TILE; ++i) A[i * FEATS + lane] = 0.f;
    if (b >= NB) return;

    const int beg = bstart[b], end = bstart[b + 1];

    // gather loop: DEPTH edges per batch; all 64 lanes work on the same edge
    // (lane = feature), so each thread only ever RMWs its own lane column.
    int e = beg;
    for (; e + DEPTH <= end; e += DEPTH) {
        unsigned v[DEPTH];
        float    x[DEPTH];
#pragma unroll
        for (int j = 0; j < DEPTH; ++j) v[j] = packed[e + j];
#pragma unroll
        for (int j = 0; j < DEPTH; ++j)
            x[j] = hs[(size_t)(v[j] & 0x3FFFFFFu) * FEATS + lane];
#pragma unroll
        for (int j = 0; j < DEPTH; ++j)
            A[(v[j] >> 26) * FEATS + lane] += x[j];
    }
    for (; e < end; ++e) {
        const unsigned v = packed[e];
        A[(v >> 26) * FEATS + lane] += hs[(size_t)(v & 0x3FFFFFFu) * FEATS + lane];
    }

    // W column `lane` into registers (coalesced across lanes per k)
    float wc[FEATS];
#pragma unroll
    for (int k = 0; k < FEATS; ++k) wc[k] = W[k * FEATS + lane];
    const float bi = bias[lane];

    // epilogue: project each accumulated row, scale, bias, act, (next prescale)
    const int node0 = b * TILE;
#pragma unroll
    for (int i = 0; i < TILE; ++i) {
        const int node = node0 + i;
        if (node >= N) break;
        const float* Ar = &A[i * FEATS];
        float s = 0.f;
#pragma unroll
        for (int k = 0; k < FEATS; ++k)
            s = fmaf(Ar[k], wc[k], s);          // wave-uniform LDS broadcast reads
        const float nv = norm[node];
        float o = fmaf(s, nv, bi);
        if (mode) o = fmaxf(o, 0.f) * nv;       // relu + next layer's pre-scale
        out[(size_t)node * FEATS + lane] = o;
    }
}

extern "C" void kernel_launch(void* const* d_in, const int* in_sizes, int n_in,
                              void* d_out, int out_size, void* d_ws, size_t ws_size,
                              hipStream_t stream) {
    const float* feat = (const float*)d_in[0];
    const float* norm = (const float*)d_in[1];
    const int*   src  = (const int*)d_in[2];
    const int*   dst  = (const int*)d_in[3];
    const float* W0   = (const float*)d_in[4];
    const float* b0   = (const float*)d_in[5];
    const float* W1   = (const float*)d_in[6];
    const float* b1   = (const float*)d_in[7];
    const float* W2   = (const float*)d_in[8];
    const float* b2   = (const float*)d_in[9];

    float* out = (float*)d_out;
    const int N = in_sizes[0] / FEATS;
    const int E = in_sizes[2];
    const int NB = (N + TILE - 1) / TILE;          // 6250
    const int NCHUNK = (E + CH - 1) / CH;          // 49

    // workspace layout (~33.3 MB)
    float*    C      = (float*)d_ws;                       // [N*64] hs ping buffer
    unsigned* packed = (unsigned*)(C + (size_t)N * FEATS); // [E]
    int*      hist   = (int*)(packed + E);                 // [NCHUNK*NB]
    int*      btotal = hist + (size_t)NCHUNK * NB;         // [NB]
    int*      bstart = btotal + NB;                        // [NB+1]

    // ---- build bucketed edge list (once, reused by 3 layers) ----
    hist_pass<<<NCHUNK, 1024, 0, stream>>>(dst, hist, E, NB);
    bucket_scan<<<NB, 256, 0, stream>>>(hist, btotal, NB, NCHUNK);
    base_scan<<<1, 1024, 0, stream>>>(btotal, bstart, NB, E);
    scatter_pack<<<NCHUNK, 1024, 0, stream>>>(src, dst, hist, bstart, packed, E, NB);

    const int agrid = (NB + 3) / 4;                // 1563
    const int sgrid = (N * 16 + 255) / 256;        // N*64/4 float4 elems

    // hs0 = feat·norm
    scale_kernel<<<sgrid, 256, 0, stream>>>(feat, norm, C, N * 16);

    // layer 0: C -> out   out = relu((agg C)@W0·norm + b0)·norm  (= hs1)
    agg_proj<<<agrid, 256, 0, stream>>>(packed, bstart, C, norm, W0, b0, out, N, NB, 1);
    // layer 1: out -> C   (= hs2)
    agg_proj<<<agrid, 256, 0, stream>>>(packed, bstart, out, norm, W1, b1, C, N, NB, 1);
    // layer 2: C -> out   final: (agg C)@W2·norm + b2  (no relu, no prescale)
    agg_proj<<<agrid, 256, 0, stream>>>(packed, bstart, C, norm, W2, b2, out, N, NB, 0);
}

// Round 6
// 329.803 us; speedup vs baseline: 4.2342x; 1.0781x over previous
//
#include <hip/hip_runtime.h>

#define FEATS 64
#define TILE 16          // dst nodes per bucket
#define MAX_NB 6400      // supports N <= 102400 at TILE=16
#define CH 8192          // edges per build chunk (196 chunks)
#define DEPTH 8          // gather batch size (double-buffered -> 16 in flight)
#define SORT_CAP 2048    // max bucket size the sorter handles (avg is 256)

// ---- scale: hs = feat * norm (float4-vectorized) ----
__global__ __launch_bounds__(256) void scale_kernel(
    const float* __restrict__ feat, const float* __restrict__ norm,
    float* __restrict__ out, int n16) {
    const int i = blockIdx.x * 256 + threadIdx.x;
    if (i >= n16) return;
    float4 v = reinterpret_cast<const float4*>(feat)[i];
    const float nv = norm[i >> 4];
    v.x *= nv; v.y *= nv; v.z *= nv; v.w *= nv;
    reinterpret_cast<float4*>(out)[i] = v;
}

// ---- build pass 1: per-chunk histogram over dst buckets ----
__global__ __launch_bounds__(1024) void hist_pass(
    const int* __restrict__ dst, int* __restrict__ hist, int E, int NB) {
    __shared__ int lh[MAX_NB];
    for (int i = threadIdx.x; i < NB; i += 1024) lh[i] = 0;
    __syncthreads();
    const int k  = blockIdx.x;
    const int e0 = k * CH, e1 = min(E, e0 + CH);
    for (int e = e0 + threadIdx.x; e < e1; e += 1024)
        atomicAdd(&lh[dst[e] >> 4], 1);
    __syncthreads();
    for (int b = threadIdx.x; b < NB; b += 1024)
        hist[(size_t)k * NB + b] = lh[b];
}

// ---- build pass 2: per-bucket exclusive scan across chunks (in place), totals ----
__global__ __launch_bounds__(256) void bucket_scan(
    int* hist, int* __restrict__ btotal, int NB, int NCHUNK) {
    __shared__ int sa[256], sb[256];
    const int b = blockIdx.x, t = threadIdx.x;
    const int v = (t < NCHUNK) ? hist[(size_t)t * NB + b] : 0;
    sa[t] = v;
    __syncthreads();
    int *cur = sa, *nxt = sb;
    for (int off = 1; off < 256; off <<= 1) {
        nxt[t] = cur[t] + ((t >= off) ? cur[t - off] : 0);
        __syncthreads();
        int* tmp = cur; cur = nxt; nxt = tmp;
    }
    if (t < NCHUNK) hist[(size_t)t * NB + b] = cur[t] - v;   // exclusive
    if (t == 255) btotal[b] = cur[255];
}

// ---- build pass 3: single-block chunked exclusive scan of bucket totals ----
__global__ __launch_bounds__(1024) void base_scan(
    const int* __restrict__ btotal, int* __restrict__ bstart, int NB, int E) {
    __shared__ int sa[1024], sb[1024];
    __shared__ int carry;
    const int t = threadIdx.x;
    if (t == 0) carry = 0;
    __syncthreads();
    for (int base = 0; base < NB; base += 1024) {
        const int i = base + t;
        const int v = (i < NB) ? btotal[i] : 0;
        sa[t] = v;
        __syncthreads();
        int *cur = sa, *nxt = sb;
        for (int off = 1; off < 1024; off <<= 1) {
            nxt[t] = cur[t] + ((t >= off) ? cur[t - off] : 0);
            __syncthreads();
            int* tmp = cur; cur = nxt; nxt = tmp;
        }
        const int c = carry;
        if (i < NB) bstart[i] = c + cur[t] - v;
        __syncthreads();
        if (t == 1023) carry = c + cur[1023];
        __syncthreads();
    }
    if (t == 0) bstart[NB] = E;
}

// ---- build pass 4: scatter packed (dstlow<<26 | src) via per-block LDS cursors ----
__global__ __launch_bounds__(1024) void scatter_pack(
    const int* __restrict__ src, const int* __restrict__ dst,
    const int* __restrict__ prebase, const int* __restrict__ bstart,
    unsigned int* __restrict__ packed, int E, int NB) {
    __shared__ int cur[MAX_NB];
    const int k = blockIdx.x;
    for (int b = threadIdx.x; b < NB; b += 1024)
        cur[b] = bstart[b] + prebase[(size_t)k * NB + b];
    __syncthreads();
    const int e0 = k * CH, e1 = min(E, e0 + CH);
    for (int e = e0 + threadIdx.x; e < e1; e += 1024) {
        const int d = dst[e];
        const int p = atomicAdd(&cur[d >> 4], 1);
        packed[p] = ((unsigned)(d & 15) << 26) | (unsigned)src[e];
    }
}

// ---- build pass 5: in-place counting sort of each bucket by dst-low ----
// Grouping enables run-length accumulation in agg_proj. If a bucket exceeds
// SORT_CAP it is left unsorted -- agg_proj's accumulate-flush stays correct.
__global__ __launch_bounds__(256) void sort_bucket(
    unsigned int* packed, const int* __restrict__ bstart, int NB) {
    __shared__ unsigned ent[SORT_CAP];
    __shared__ int cnt[16];
    const int b = blockIdx.x;
    const int beg = bstart[b], end = bstart[b + 1];
    const int n = end - beg;
    if (n > SORT_CAP) return;           // uniform per block: safe
    const int t = threadIdx.x;
    if (t < 16) cnt[t] = 0;
    __syncthreads();
    for (int i = t; i < n; i += 256) {
        const unsigned v = packed[beg + i];
        ent[i] = v;
        atomicAdd(&cnt[v >> 26], 1);
    }
    __syncthreads();
    if (t == 0) {                        // tiny exclusive scan -> group starts
        int run = 0;
        for (int i = 0; i < 16; ++i) { const int c = cnt[i]; cnt[i] = run; run += c; }
    }
    __syncthreads();
    for (int i = t; i < n; i += 256) {
        const unsigned v = ent[i];
        const int p = atomicAdd(&cnt[v >> 26], 1);
        packed[beg + p] = v;
    }
}

// ---- fused aggregate + project: TWO waves per bucket, run-length accumulation ----
__global__ __launch_bounds__(256) void agg_proj(
    const unsigned int* __restrict__ packed, const int* __restrict__ bstart,
    const float* __restrict__ hs, const float* __restrict__ norm,
    const float* __restrict__ W, const float* __restrict__ bias,
    float* __restrict__ out, int N, int NB, int mode) {
    __shared__ float acc[4][TILE * FEATS];     // 4 stripes x 4 KB, wave-private
    const int lane = threadIdx.x & 63;
    const int w    = threadIdx.x >> 6;
    const int lb   = w >> 1;                   // local bucket (0,1)
    const int hf   = w & 1;                    // which half of the edge range
    const int b    = blockIdx.x * 2 + lb;
    float* A = acc[w];
#pragma unroll
    for (int i = 0; i < TILE; ++i) A[i * FEATS + lane] = 0.f;

    if (b < NB) {
        const int beg = bstart[b], end = bstart[b + 1];
        const int half = (end - beg) >> 1;
        int e        = beg + hf * half;
        const int e1 = hf ? end : (beg + half);
        if (e < e1) {
            int   cur  = (int)((unsigned)__builtin_amdgcn_readfirstlane((int)packed[e]) >> 26);
            float racc = 0.f;

            unsigned va[DEPTH], vb[DEPTH];
            float    xa[DEPTH], xb[DEPTH];

            // run-length consume of one batch (order-preserving)
            auto consume = [&](const unsigned* vv, const float* xx) {
#pragma unroll
                for (int j = 0; j < DEPTH; ++j) {
                    const int dl = (int)(vv[j] >> 26);
                    if (dl != cur) {               // wave-uniform branch (scalar dl)
                        A[cur * FEATS + lane] += racc;
                        racc = 0.f;
                        cur  = dl;
                    }
                    racc += xx[j];
                }
            };
            auto loadV = [&](int e0, unsigned* vv) {
#pragma unroll
                for (int j = 0; j < DEPTH; ++j)
                    vv[j] = (unsigned)__builtin_amdgcn_readfirstlane((int)packed[e0 + j]);
            };
            auto loadX = [&](const unsigned* vv, float* xx) {
#pragma unroll
                for (int j = 0; j < DEPTH; ++j)
                    xx[j] = hs[(size_t)(vv[j] & 0x3FFFFFFu) * FEATS + lane];
            };

            const int nfull = (e1 - e) / DEPTH;
            if (nfull > 0) {
                loadV(e, va); loadX(va, xa);
                for (int k = 1; k < nfull; ++k) {
                    if (k & 1) { loadV(e + k * DEPTH, vb); consume(va, xa); loadX(vb, xb); }
                    else       { loadV(e + k * DEPTH, va); consume(vb, xb); loadX(va, xa); }
                }
                if (nfull & 1) consume(va, xa); else consume(vb, xb);
                e += nfull * DEPTH;
            }
            for (; e < e1; ++e) {                  // tail, scalar
                const unsigned v = (unsigned)__builtin_amdgcn_readfirstlane((int)packed[e]);
                const int dl = (int)(v >> 26);
                const float x = hs[(size_t)(v & 0x3FFFFFFu) * FEATS + lane];
                if (dl != cur) { A[cur * FEATS + lane] += racc; racc = 0.f; cur = dl; }
                racc += x;
            }
            A[cur * FEATS + lane] += racc;         // final flush
        }
    }
    __syncthreads();

    if (b < NB) {
        // merge partner stripe into main stripe -- each wave merges exactly the
        // float range of the nodes it will project (no further sync needed).
        float4* M = reinterpret_cast<float4*>(acc[lb * 2]);
        float4* X = reinterpret_cast<float4*>(acc[lb * 2 + 1]);
#pragma unroll
        for (int r = 0; r < 2; ++r) {
            const int t4 = hf * 128 + r * 64 + lane;
            float4 m = M[t4];
            const float4 x = X[t4];
            m.x += x.x; m.y += x.y; m.z += x.z; m.w += x.w;
            M[t4] = m;
        }

        float wc[FEATS];
#pragma unroll
        for (int k = 0; k < FEATS; ++k) wc[k] = W[k * FEATS + lane];
        const float bi = bias[lane];

        const float* Am = acc[lb * 2];
        const int node0 = b * TILE + hf * 8;
#pragma unroll
        for (int i = 0; i < 8; ++i) {
            const int node = node0 + i;
            if (node >= N) break;
            const float4* Ar = reinterpret_cast<const float4*>(&Am[(hf * 8 + i) * FEATS]);
            float s = 0.f;
#pragma unroll
            for (int k4 = 0; k4 < 16; ++k4) {
                const float4 a = Ar[k4];           // wave-uniform ds_read_b128
                s = fmaf(a.x, wc[4 * k4 + 0], s);
                s = fmaf(a.y, wc[4 * k4 + 1], s);
                s = fmaf(a.z, wc[4 * k4 + 2], s);
                s = fmaf(a.w, wc[4 * k4 + 3], s);
            }
            const float nv = norm[node];
            float o = fmaf(s, nv, bi);
            if (mode) o = fmaxf(o, 0.f) * nv;      // relu + next layer's pre-scale
            out[(size_t)node * FEATS + lane] = o;
        }
    }
}

extern "C" void kernel_launch(void* const* d_in, const int* in_sizes, int n_in,
                              void* d_out, int out_size, void* d_ws, size_t ws_size,
                              hipStream_t stream) {
    const float* feat = (const float*)d_in[0];
    const float* norm = (const float*)d_in[1];
    const int*   src  = (const int*)d_in[2];
    const int*   dst  = (const int*)d_in[3];
    const float* W0   = (const float*)d_in[4];
    const float* b0   = (const float*)d_in[5];
    const float* W1   = (const float*)d_in[6];
    const float* b1   = (const float*)d_in[7];
    const float* W2   = (const float*)d_in[8];
    const float* b2   = (const float*)d_in[9];

    float* out = (float*)d_out;
    const int N = in_sizes[0] / FEATS;
    const int E = in_sizes[2];
    const int NB = (N + TILE - 1) / TILE;          // 6250
    const int NCHUNK = (E + CH - 1) / CH;          // 196

    // workspace layout (~37 MB)
    float*    C      = (float*)d_ws;                       // [N*64] ping buffer
    unsigned* packed = (unsigned*)(C + (size_t)N * FEATS); // [E]
    int*      hist   = (int*)(packed + E);                 // [NCHUNK*NB]
    int*      btotal = hist + (size_t)NCHUNK * NB;         // [NB]
    int*      bstart = btotal + NB;                        // [NB+1]

    // ---- build sorted-bucket edge list (once, reused by 3 layers) ----
    hist_pass<<<NCHUNK, 1024, 0, stream>>>(dst, hist, E, NB);
    bucket_scan<<<NB, 256, 0, stream>>>(hist, btotal, NB, NCHUNK);
    base_scan<<<1, 1024, 0, stream>>>(btotal, bstart, NB, E);
    scatter_pack<<<NCHUNK, 1024, 0, stream>>>(src, dst, hist, bstart, packed, E, NB);
    sort_bucket<<<NB, 256, 0, stream>>>(packed, bstart, NB);

    const int agrid = (NB + 1) / 2;                // 2 buckets per block
    const int sgrid = (N * 16 + 255) / 256;

    // hs0 = feat*norm
    scale_kernel<<<sgrid, 256, 0, stream>>>(feat, norm, C, N * 16);

    // layer 0: C -> out   out = relu((agg C)@W0*norm + b0)*norm
    agg_proj<<<agrid, 256, 0, stream>>>(packed, bstart, C, norm, W0, b0, out, N, NB, 1);
    // layer 1: out -> C
    agg_proj<<<agrid, 256, 0, stream>>>(packed, bstart, out, norm, W1, b1, C, N, NB, 1);
    // layer 2: C -> out   final (no relu, no prescale)
    agg_proj<<<agrid, 256, 0, stream>>>(packed, bstart, C, norm, W2, b2, out, N, NB, 0);
}

// Round 7
// 306.121 us; speedup vs baseline: 4.5618x; 1.0774x over previous
//
#include <hip/hip_runtime.h>

#define FEATS 64
#define TILE 16          // dst nodes per bucket
#define MAX_NB 6400      // supports N <= 102400 at TILE=16
#define CH 8192          // edges per build chunk (196 chunks)
#define DEPTH 16         // gather batch size (double-buffered -> 32 in flight)
#define SORT_CAP 2048    // max bucket size the sorter handles (avg is 256)

__device__ __forceinline__ float bf2f(unsigned short b) {
    unsigned u = (unsigned)b << 16;
    float f; __builtin_memcpy(&f, &u, 4); return f;
}
__device__ __forceinline__ unsigned short f2bf(float f) {   // round-to-nearest-even
    unsigned u; __builtin_memcpy(&u, &f, 4);
    u += 0x7FFFu + ((u >> 16) & 1u);
    return (unsigned short)(u >> 16);
}

// ---- scale: hs = bf16(feat * norm); 4 elems/thread ----
__global__ __launch_bounds__(256) void scale_kernel(
    const float* __restrict__ feat, const float* __restrict__ norm,
    unsigned short* __restrict__ out, int n4) {
    const int i = blockIdx.x * 256 + threadIdx.x;
    if (i >= n4) return;
    float4 v = reinterpret_cast<const float4*>(feat)[i];
    const float nv = norm[i >> 4];                  // 16 float4 per 64-feat row
    uint2 p;
    p.x = (unsigned)f2bf(v.x * nv) | ((unsigned)f2bf(v.y * nv) << 16);
    p.y = (unsigned)f2bf(v.z * nv) | ((unsigned)f2bf(v.w * nv) << 16);
    reinterpret_cast<uint2*>(out)[i] = p;
}

// ---- build pass 1: per-chunk histogram over dst buckets ----
__global__ __launch_bounds__(1024) void hist_pass(
    const int* __restrict__ dst, int* __restrict__ hist, int E, int NB) {
    __shared__ int lh[MAX_NB];
    for (int i = threadIdx.x; i < NB; i += 1024) lh[i] = 0;
    __syncthreads();
    const int k  = blockIdx.x;
    const int e0 = k * CH, e1 = min(E, e0 + CH);
    for (int e = e0 + threadIdx.x; e < e1; e += 1024)
        atomicAdd(&lh[dst[e] >> 4], 1);
    __syncthreads();
    for (int b = threadIdx.x; b < NB; b += 1024)
        hist[(size_t)k * NB + b] = lh[b];
}

// ---- build pass 2: per-bucket exclusive scan across chunks (in place), totals ----
__global__ __launch_bounds__(256) void bucket_scan(
    int* hist, int* __restrict__ btotal, int NB, int NCHUNK) {
    __shared__ int sa[256], sb[256];
    const int b = blockIdx.x, t = threadIdx.x;
    const int v = (t < NCHUNK) ? hist[(size_t)t * NB + b] : 0;
    sa[t] = v;
    __syncthreads();
    int *cur = sa, *nxt = sb;
    for (int off = 1; off < 256; off <<= 1) {
        nxt[t] = cur[t] + ((t >= off) ? cur[t - off] : 0);
        __syncthreads();
        int* tmp = cur; cur = nxt; nxt = tmp;
    }
    if (t < NCHUNK) hist[(size_t)t * NB + b] = cur[t] - v;   // exclusive
    if (t == 255) btotal[b] = cur[255];
}

// ---- build pass 3: single-block chunked exclusive scan of bucket totals ----
__global__ __launch_bounds__(1024) void base_scan(
    const int* __restrict__ btotal, int* __restrict__ bstart, int NB, int E) {
    __shared__ int sa[1024], sb[1024];
    __shared__ int carry;
    const int t = threadIdx.x;
    if (t == 0) carry = 0;
    __syncthreads();
    for (int base = 0; base < NB; base += 1024) {
        const int i = base + t;
        const int v = (i < NB) ? btotal[i] : 0;
        sa[t] = v;
        __syncthreads();
        int *cur = sa, *nxt = sb;
        for (int off = 1; off < 1024; off <<= 1) {
            nxt[t] = cur[t] + ((t >= off) ? cur[t - off] : 0);
            __syncthreads();
            int* tmp = cur; cur = nxt; nxt = tmp;
        }
        const int c = carry;
        if (i < NB) bstart[i] = c + cur[t] - v;
        __syncthreads();
        if (t == 1023) carry = c + cur[1023];
        __syncthreads();
    }
    if (t == 0) bstart[NB] = E;
}

// ---- build pass 4: scatter packed (dstlow<<26 | src) via per-block LDS cursors ----
__global__ __launch_bounds__(1024) void scatter_pack(
    const int* __restrict__ src, const int* __restrict__ dst,
    const int* __restrict__ prebase, const int* __restrict__ bstart,
    unsigned int* __restrict__ packed, int E, int NB) {
    __shared__ int cur[MAX_NB];
    const int k = blockIdx.x;
    for (int b = threadIdx.x; b < NB; b += 1024)
        cur[b] = bstart[b] + prebase[(size_t)k * NB + b];
    __syncthreads();
    const int e0 = k * CH, e1 = min(E, e0 + CH);
    for (int e = e0 + threadIdx.x; e < e1; e += 1024) {
        const int d = dst[e];
        const int p = atomicAdd(&cur[d >> 4], 1);
        packed[p] = ((unsigned)(d & 15) << 26) | (unsigned)src[e];
    }
}

// ---- build pass 5: in-place counting sort of each bucket by dst-low ----
__global__ __launch_bounds__(256) void sort_bucket(
    unsigned int* packed, const int* __restrict__ bstart, int NB) {
    __shared__ unsigned ent[SORT_CAP];
    __shared__ int cnt[16];
    const int b = blockIdx.x;
    const int beg = bstart[b], end = bstart[b + 1];
    const int n = end - beg;
    if (n > SORT_CAP) return;           // uniform per block: safe
    const int t = threadIdx.x;
    if (t < 16) cnt[t] = 0;
    __syncthreads();
    for (int i = t; i < n; i += 256) {
        const unsigned v = packed[beg + i];
        ent[i] = v;
        atomicAdd(&cnt[v >> 26], 1);
    }
    __syncthreads();
    if (t == 0) {
        int run = 0;
        for (int i = 0; i < 16; ++i) { const int c = cnt[i]; cnt[i] = run; run += c; }
    }
    __syncthreads();
    for (int i = t; i < n; i += 256) {
        const unsigned v = ent[i];
        const int p = atomicAdd(&cnt[v >> 26], 1);
        packed[beg + p] = v;
    }
}

// ---- fused aggregate + project: TWO waves per bucket, run-length accumulation ----
// hs is bf16; all accumulation fp32. mode=1: out is bf16 hs for next layer;
// mode=0: out is fp32 final.
__global__ __launch_bounds__(256) void agg_proj(
    const unsigned int* __restrict__ packed, const int* __restrict__ bstart,
    const unsigned short* __restrict__ hs, const float* __restrict__ norm,
    const float* __restrict__ W, const float* __restrict__ bias,
    void* __restrict__ outv, int N, int NB, int mode) {
    __shared__ float acc[4][TILE * FEATS];     // 4 stripes x 4 KB, wave-private
    const int lane = threadIdx.x & 63;
    const int w    = threadIdx.x >> 6;
    const int lb   = w >> 1;                   // local bucket (0,1)
    const int hf   = w & 1;                    // which half of the edge range
    const int b    = blockIdx.x * 2 + lb;
    float* A = acc[w];
#pragma unroll
    for (int i = 0; i < TILE; ++i) A[i * FEATS + lane] = 0.f;

    if (b < NB) {
        const int beg = bstart[b], end = bstart[b + 1];
        const int half = (end - beg) >> 1;
        int e        = beg + hf * half;
        const int e1 = hf ? end : (beg + half);
        if (e < e1) {
            int   cur  = (int)((unsigned)__builtin_amdgcn_readfirstlane((int)packed[e]) >> 26);
            float racc = 0.f;

            unsigned va[DEPTH], vb[DEPTH];
            float    xa[DEPTH], xb[DEPTH];

            auto consume = [&](const unsigned* vv, const float* xx) {
#pragma unroll
                for (int j = 0; j < DEPTH; ++j) {
                    const int dl = (int)(vv[j] >> 26);
                    if (dl != cur) {               // wave-uniform branch (scalar dl)
                        A[cur * FEATS + lane] += racc;
                        racc = 0.f;
                        cur  = dl;
                    }
                    racc += xx[j];
                }
            };
            auto loadV = [&](int e0, unsigned* vv) {
#pragma unroll
                for (int j = 0; j < DEPTH; ++j)
                    vv[j] = (unsigned)__builtin_amdgcn_readfirstlane((int)packed[e0 + j]);
            };
            auto loadX = [&](const unsigned* vv, float* xx) {
#pragma unroll
                for (int j = 0; j < DEPTH; ++j)
                    xx[j] = bf2f(hs[(size_t)(vv[j] & 0x3FFFFFFu) * FEATS + lane]);
            };

            const int nfull = (e1 - e) / DEPTH;
            if (nfull > 0) {
                loadV(e, va); loadX(va, xa);
                for (int k = 1; k < nfull; ++k) {
                    if (k & 1) { loadV(e + k * DEPTH, vb); consume(va, xa); loadX(vb, xb); }
                    else       { loadV(e + k * DEPTH, va); consume(vb, xb); loadX(va, xa); }
                }
                if (nfull & 1) consume(va, xa); else consume(vb, xb);
                e += nfull * DEPTH;
            }
            for (; e < e1; ++e) {                  // tail, scalar
                const unsigned v = (unsigned)__builtin_amdgcn_readfirstlane((int)packed[e]);
                const int dl = (int)(v >> 26);
                const float x = bf2f(hs[(size_t)(v & 0x3FFFFFFu) * FEATS + lane]);
                if (dl != cur) { A[cur * FEATS + lane] += racc; racc = 0.f; cur = dl; }
                racc += x;
            }
            A[cur * FEATS + lane] += racc;         // final flush
        }
    }
    __syncthreads();

    if (b < NB) {
        // merge partner stripe into main stripe (each wave merges what it projects)
        float4* M = reinterpret_cast<float4*>(acc[lb * 2]);
        float4* X = reinterpret_cast<float4*>(acc[lb * 2 + 1]);
#pragma unroll
        for (int r = 0; r < 2; ++r) {
            const int t4 = hf * 128 + r * 64 + lane;
            float4 m = M[t4];
            const float4 x = X[t4];
            m.x += x.x; m.y += x.y; m.z += x.z; m.w += x.w;
            M[t4] = m;
        }

        float wc[FEATS];
#pragma unroll
        for (int k = 0; k < FEATS; ++k) wc[k] = W[k * FEATS + lane];
        const float bi = bias[lane];

        const float* Am = acc[lb * 2];
        const int node0 = b * TILE + hf * 8;
#pragma unroll
        for (int i = 0; i < 8; ++i) {
            const int node = node0 + i;
            if (node >= N) break;
            const float4* Ar = reinterpret_cast<const float4*>(&Am[(hf * 8 + i) * FEATS]);
            float s = 0.f;
#pragma unroll
            for (int k4 = 0; k4 < 16; ++k4) {
                const float4 a = Ar[k4];           // wave-uniform ds_read_b128
                s = fmaf(a.x, wc[4 * k4 + 0], s);
                s = fmaf(a.y, wc[4 * k4 + 1], s);
                s = fmaf(a.z, wc[4 * k4 + 2], s);
                s = fmaf(a.w, wc[4 * k4 + 3], s);
            }
            const float nv = norm[node];
            float o = fmaf(s, nv, bi);
            if (mode) {                            // relu + next prescale -> bf16 hs
                o = fmaxf(o, 0.f) * nv;
                ((unsigned short*)outv)[(size_t)node * FEATS + lane] = f2bf(o);
            } else {                               // final fp32
                ((float*)outv)[(size_t)node * FEATS + lane] = o;
            }
        }
    }
}

extern "C" void kernel_launch(void* const* d_in, const int* in_sizes, int n_in,
                              void* d_out, int out_size, void* d_ws, size_t ws_size,
                              hipStream_t stream) {
    const float* feat = (const float*)d_in[0];
    const float* norm = (const float*)d_in[1];
    const int*   src  = (const int*)d_in[2];
    const int*   dst  = (const int*)d_in[3];
    const float* W0   = (const float*)d_in[4];
    const float* b0   = (const float*)d_in[5];
    const float* W1   = (const float*)d_in[6];
    const float* b1   = (const float*)d_in[7];
    const float* W2   = (const float*)d_in[8];
    const float* b2   = (const float*)d_in[9];

    float* out = (float*)d_out;
    const int N = in_sizes[0] / FEATS;
    const int E = in_sizes[2];
    const int NB = (N + TILE - 1) / TILE;          // 6250
    const int NCHUNK = (E + CH - 1) / CH;          // 196

    // workspace layout (~31 MB)
    unsigned short* H0 = (unsigned short*)d_ws;            // [N*64] bf16 ping
    unsigned short* H1 = H0 + (size_t)N * FEATS;           // [N*64] bf16 pong
    unsigned* packed = (unsigned*)(H1 + (size_t)N * FEATS);// [E]
    int*      hist   = (int*)(packed + E);                 // [NCHUNK*NB]
    int*      btotal = hist + (size_t)NCHUNK * NB;         // [NB]
    int*      bstart = btotal + NB;                        // [NB+1]

    // ---- build sorted-bucket edge list (once, reused by 3 layers) ----
    hist_pass<<<NCHUNK, 1024, 0, stream>>>(dst, hist, E, NB);
    bucket_scan<<<NB, 256, 0, stream>>>(hist, btotal, NB, NCHUNK);
    base_scan<<<1, 1024, 0, stream>>>(btotal, bstart, NB, E);
    scatter_pack<<<NCHUNK, 1024, 0, stream>>>(src, dst, hist, bstart, packed, E, NB);
    sort_bucket<<<NB, 256, 0, stream>>>(packed, bstart, NB);

    const int agrid = (NB + 1) / 2;                // 2 buckets per block
    const int sgrid = (N * 16 + 255) / 256;        // N*64/4 quads

    // hs0 = bf16(feat*norm)
    scale_kernel<<<sgrid, 256, 0, stream>>>(feat, norm, H0, N * 16);

    // layer 0: H0 -> H1 (bf16 hs1)
    agg_proj<<<agrid, 256, 0, stream>>>(packed, bstart, H0, norm, W0, b0, H1, N, NB, 1);
    // layer 1: H1 -> H0 (bf16 hs2)
    agg_proj<<<agrid, 256, 0, stream>>>(packed, bstart, H1, norm, W1, b1, H0, N, NB, 1);
    // layer 2: H0 -> out (fp32 final)
    agg_proj<<<agrid, 256, 0, stream>>>(packed, bstart, H0, norm, W2, b2, out, N, NB, 0);
}